// Round 17
// baseline (236.149 us; speedup 1.0000x reference)
//
#include <hip/hip_runtime.h>
#include <math.h>

#define GAMMA 0.1f
#define SCALE0 32768.0f
#define INV0 (1.0f / 32768.0f)
#define SCALE1 8192.0f
#define INV1 (1.0f / 8192.0f)

typedef float f32x4 __attribute__((ext_vector_type(4)));
typedef short short4v __attribute__((ext_vector_type(4)));
typedef short short8 __attribute__((ext_vector_type(8)));

static __device__ __forceinline__ unsigned short f2bf(float f) {
  union { float f; unsigned u; } v; v.f = f;
  unsigned r = v.u + 0x7FFF + ((v.u >> 16) & 1);   // RNE
  return (unsigned short)(r >> 16);
}
static __device__ __forceinline__ float bf2f(unsigned short b) {
  union { unsigned u; float f; } v; v.u = ((unsigned)b) << 16;
  return v.f;
}

// ---------------------------------------------------------------------------
// Fused setup: zero counters + build both K-chunk-major Bt matrices.
// blocks [0,4): zero bcnt2 (2*391 ints); [4,164): Bt0; [164,172): Bt1.
// ---------------------------------------------------------------------------
__global__ __launch_bounds__(256) void setup_fused(
    int* __restrict__ bcnt2, int ncnt,
    const float* __restrict__ W0, const float* __restrict__ sc0,
    const float* __restrict__ dk0, unsigned short* __restrict__ Bt0, int F,
    const float* __restrict__ W1, const float* __restrict__ sc1,
    const float* __restrict__ dk1, unsigned short* __restrict__ Bt1) {
  int b = blockIdx.x;
  int t = threadIdx.x;
  if (b < 4) {
    int i = b * 256 + t;
    if (i < ncnt) bcnt2[i] = 0;
  } else if (b < 164) {
    int i = (b - 4) * 256 + t;           // [0, 40960)
    int c = i >> 9;                      // /512
    int k = i & 511;
    float v = 0.f;
    if (k < F) {
      if (c < 64) v = W0[(size_t)k * 64 + c];
      else if (c == 64) v = sc0[k];
      else if (c == 65) v = dk0[k];
    }
    Bt0[(size_t)((k >> 3) * 80 + c) * 8 + (k & 7)] = f2bf(v);
  } else {
    int i = (b - 164) * 256 + t;         // [0, 2048)
    int c = i >> 6;                      // /64
    int k = i & 63;
    float v;
    if (c < 16) v = W1[(size_t)k * 16 + c];
    else if (c == 16) v = sc1[k];
    else if (c == 17) v = dk1[k];
    else v = 0.f;
    Bt1[(size_t)((k >> 3) * 32 + c) * 8 + (k & 7)] = f2bf(v);
  }
}

// ---------------------------------------------------------------------------
// Layer-0 fused MFMA linear, LDS-staged A (R13/R16 struct, unchanged).
// ---------------------------------------------------------------------------
template <int CFRAGS, int OUTFRAGS, int COLS>
__global__ __launch_bounds__(256) void mfma_linear_l0(
    const float* __restrict__ A, const unsigned short* __restrict__ Bt3,
    const float* __restrict__ sb, const float* __restrict__ db,
    unsigned short* __restrict__ outW, float* __restrict__ s,
    float* __restrict__ Dk, int N, int Kact) {
  constexpr int KPAD = 512;
  constexpr int KSPLIT = 4, RPB = 16;
  constexpr int KS_PER = (KPAD / 32) / KSPLIT;     // 4
  constexpr int H = OUTFRAGS * 16;
  __shared__ unsigned short Ald[RPB * KPAD];                  // 16 KB
  __shared__ float red[(KSPLIT - 1) * 64 * CFRAGS * 4];       // 15 KB

  const int t = threadIdx.x;
  const int rowBase = blockIdx.x * RPB;

#pragma unroll
  for (int it = 0; it < (RPB * KPAD) / (256 * 4); ++it) {
    int li = it * 1024 + t * 4;
    int row = li >> 9;
    int col = li & 511;
    int grow = rowBase + row;
    f32x4 v = (f32x4)0.f;
    if (grow < N && col < Kact)
      v = *(const f32x4*)(A + (size_t)grow * Kact + col);
    short4v b;
#pragma unroll
    for (int j = 0; j < 4; ++j) b[j] = (short)f2bf(v[j]);
    int byte = row * (KPAD * 2) + ((col * 2) ^ ((row & 7) << 4));
    *(short4v*)((char*)Ald + byte) = b;
  }
  __syncthreads();

  const int kslice = t >> 6;          // 0..3
  const int l = t & 63;
  const int kgrp = l >> 4;
  const int lc = l & 15;
  const int lrow = lc;
  const int rowD = rowBase + kgrp * 4;

  f32x4 acc[CFRAGS];
#pragma unroll
  for (int i = 0; i < CFRAGS; ++i) acc[i] = (f32x4)0.f;

  const int rbyte = lrow * (KPAD * 2);
  const int rswz = (lrow & 7) << 4;
#pragma unroll
  for (int kk = 0; kk < KS_PER; ++kk) {
    const int ks = kslice * KS_PER + kk;
    short8 av = *(const short8*)((char*)Ald +
                                 (rbyte + ((ks * 64 + kgrp * 16) ^ rswz)));
    const unsigned short* bbase =
        Bt3 + (size_t)((ks * 4 + kgrp) * COLS + lc) * 8;
#pragma unroll
    for (int fc = 0; fc < CFRAGS; ++fc) {
      short8 bv = *(const short8*)(bbase + fc * 128);
      acc[fc] = __builtin_amdgcn_mfma_f32_16x16x32_bf16(av, bv, acc[fc], 0, 0, 0);
    }
  }

  if (kslice > 0) {
    float* dst = red + ((kslice - 1) * 64 + l) * (CFRAGS * 4);
#pragma unroll
    for (int fc = 0; fc < CFRAGS; ++fc)
#pragma unroll
      for (int r = 0; r < 4; ++r) dst[fc * 4 + r] = acc[fc][r];
  }
  __syncthreads();
  if (kslice == 0) {
#pragma unroll
    for (int s2 = 1; s2 < KSPLIT; ++s2) {
      const float* src2 = red + ((s2 - 1) * 64 + l) * (CFRAGS * 4);
#pragma unroll
      for (int fc = 0; fc < CFRAGS; ++fc)
#pragma unroll
        for (int r = 0; r < 4; ++r) acc[fc][r] += src2[fc * 4 + r];
    }
#pragma unroll
    for (int fc = 0; fc < OUTFRAGS; ++fc) {
#pragma unroll
      for (int r = 0; r < 4; ++r) {
        int gr = rowD + r;
        if (gr < N) outW[(size_t)gr * H + fc * 16 + lc] = f2bf(acc[fc][r]);
      }
    }
    if (lc < 2) {
      f32x4 g = acc[CFRAGS - 1];
#pragma unroll
      for (int r = 0; r < 4; ++r) {
        int gr = rowD + r;
        if (gr < N) {
          if (lc == 0) s[gr] = 1.f / (1.f + expf(-(g[r] + sb[0])));
          else Dk[gr] = g[r] + db[0];
        }
      }
    }
  }
}

// ---------------------------------------------------------------------------
// Layer-1 fused MFMA linear (bf16 A, K=64). Unchanged.
// ---------------------------------------------------------------------------
template <int KPAD, int CFRAGS, int OUTFRAGS, int COLS>
__global__ __launch_bounds__(256) void mfma_linear_bf(
    const unsigned short* __restrict__ Aptr, const unsigned short* __restrict__ Bt3,
    const float* __restrict__ sb, const float* __restrict__ db,
    unsigned short* __restrict__ outW, float* __restrict__ s,
    float* __restrict__ Dk, int N, int Kact) {
  constexpr int H = OUTFRAGS * 16;
  constexpr int KSPLIT = 2, RG = 2, RPB = 32;
  constexpr int KS_PER = (KPAD / 32) / KSPLIT;
  __shared__ float red[(KSPLIT - 1) * RG * 64 * CFRAGS * 4];

  const int w = threadIdx.x >> 6;
  const int rowgrp = w % RG;
  const int kslice = w / RG;
  const int l = threadIdx.x & 63;
  const int kgrp = l >> 4;
  const int lc = l & 15;
  const int rowA = blockIdx.x * RPB + rowgrp * 16 + lc;
  const int rowD = blockIdx.x * RPB + rowgrp * 16 + kgrp * 4;
  const int rowSafe = (rowA < N) ? rowA : 0;

  f32x4 acc[CFRAGS];
#pragma unroll
  for (int i = 0; i < CFRAGS; ++i) acc[i] = (f32x4)0.f;

#pragma unroll
  for (int kk = 0; kk < KS_PER; ++kk) {
    const int ks = kslice * KS_PER + kk;
    const int kb = ks * 32 + kgrp * 8;
    short8 av = *(const short8*)(Aptr + (size_t)rowSafe * Kact + kb);
    const unsigned short* bbase =
        Bt3 + (size_t)((ks * 4 + kgrp) * COLS + lc) * 8;
#pragma unroll
    for (int fc = 0; fc < CFRAGS; ++fc) {
      short8 bv = *(const short8*)(bbase + fc * 128);
      acc[fc] = __builtin_amdgcn_mfma_f32_16x16x32_bf16(av, bv, acc[fc], 0, 0, 0);
    }
  }

  if (kslice > 0) {
    float* dst = red + ((rowgrp)*64 + l) * (CFRAGS * 4);
#pragma unroll
    for (int fc = 0; fc < CFRAGS; ++fc)
#pragma unroll
      for (int r = 0; r < 4; ++r) dst[fc * 4 + r] = acc[fc][r];
  }
  __syncthreads();
  if (kslice == 0) {
    const float* src2 = red + ((rowgrp)*64 + l) * (CFRAGS * 4);
#pragma unroll
    for (int fc = 0; fc < CFRAGS; ++fc)
#pragma unroll
      for (int r = 0; r < 4; ++r) acc[fc][r] += src2[fc * 4 + r];

#pragma unroll
    for (int fc = 0; fc < OUTFRAGS; ++fc) {
#pragma unroll
      for (int r = 0; r < 4; ++r) {
        int gr = rowD + r;
        if (gr < N) outW[(size_t)gr * H + fc * 16 + lc] = f2bf(acc[fc][r]);
      }
    }
    if (lc < 2) {
      f32x4 g = acc[CFRAGS - 1];
#pragma unroll
      for (int r = 0; r < 4; ++r) {
        int gr = rowD + r;
        if (gr < N) {
          if (lc == 0) s[gr] = 1.f / (1.f + expf(-(g[r] + sb[0])));
          else Dk[gr] = g[r] + db[0];
        }
      }
    }
  }
}

// ---------------------------------------------------------------------------
// Tile binning, 128-node tiles (bucket = dst >> 7, nb = 391 <= 512).
// INT atomics only. bucket_count saves per-chunk counts (R16).
// ---------------------------------------------------------------------------
#define BIN_CHUNK 8192

__global__ __launch_bounds__(512) void bucket_count2(
    const int* __restrict__ eiA, int EA, int* __restrict__ bcntA,
    const int* __restrict__ eiK, int EK, int* __restrict__ bcntK, int nchA,
    int* __restrict__ pcnt) {
  const int* ei;
  int E, chunk;
  int* bcnt;
  if (blockIdx.x < nchA) { ei = eiA; E = EA; bcnt = bcntA; chunk = blockIdx.x; }
  else { ei = eiK; E = EK; bcnt = bcntK; chunk = blockIdx.x - nchA; }
  __shared__ int lc[512];
  lc[threadIdx.x] = 0;
  __syncthreads();
  const int base = chunk * BIN_CHUNK;
  for (int k = threadIdx.x; k < BIN_CHUNK; k += 512) {
    int e = base + k;
    if (e < E) atomicAdd(&lc[ei[E + e] >> 7], 1);
  }
  __syncthreads();
  {
    int c = lc[threadIdx.x];
    pcnt[blockIdx.x * 512 + threadIdx.x] = c;   // saved for bin_fill
    if (c) atomicAdd(&bcnt[threadIdx.x], c);
  }
}

__global__ __launch_bounds__(512) void bucket_scan2(
    int* __restrict__ bcntA, int* __restrict__ boffA, int* __restrict__ gcurA,
    int* __restrict__ bcntK, int* __restrict__ boffK, int* __restrict__ gcurK,
    int nb) {
  int* bcnt = blockIdx.x ? bcntK : bcntA;
  int* boff = blockIdx.x ? boffK : boffA;
  int* gcur = blockIdx.x ? gcurK : gcurA;
  __shared__ int sh[512];
  int t = threadIdx.x;
  int v = (t < nb) ? bcnt[t] : 0;
  sh[t] = v;
  __syncthreads();
  int acc = v;
  for (int off = 1; off < 512; off <<= 1) {
    int xx = (t >= off) ? sh[t - off] : 0;
    __syncthreads();
    acc += xx;
    sh[t] = acc;
    __syncthreads();
  }
  if (t < nb) {
    boff[t] = acc - v;
    gcur[t] = acc - v;
  }
  if (t == nb - 1) boff[nb] = acc;
}

// Raw record: {x = (dst&127)<<16 | src, y = fp32 weight bits}
__global__ __launch_bounds__(512) void bin_fill2(
    const int* __restrict__ eiA, const float* __restrict__ ewA, int EA,
    int* __restrict__ gcurA, int2* __restrict__ recA,
    const int* __restrict__ eiK, const float* __restrict__ ewK, int EK,
    int* __restrict__ gcurK, int2* __restrict__ recK, int nchA,
    const int* __restrict__ pcnt) {
  const int* ei;
  const float* ew;
  int E, chunk;
  int* gcur;
  int2* rec;
  if (blockIdx.x < nchA) {
    ei = eiA; ew = ewA; E = EA; gcur = gcurA; rec = recA; chunk = blockIdx.x;
  } else {
    ei = eiK; ew = ewK; E = EK; gcur = gcurK; rec = recK;
    chunk = blockIdx.x - nchA;
  }
  __shared__ int scur[512];
  {
    int c = pcnt[blockIdx.x * 512 + threadIdx.x];
    scur[threadIdx.x] = c ? atomicAdd(&gcur[threadIdx.x], c) : 0;
  }
  __syncthreads();
  const int base = chunk * BIN_CHUNK;
  for (int k = threadIdx.x; k < BIN_CHUNK; k += 512) {
    int e = base + k;
    if (e < E) {
      int src = ei[e];
      int dst = ei[E + e];
      int pos = atomicAdd(&scur[dst >> 7], 1);
      rec[pos] = make_int2(((dst & 127) << 16) | src, __float_as_int(ew[e]));
    }
  }
}

// ---------------------------------------------------------------------------
// aggfix64: layer-0 aggregation + combine, one block per 128-node tile.
// Fixed-point INT LDS atomics (native ds_add; R5 lesson: fp32 LDS atomics
// are CAS loops — int is fine; int adds are associative => deterministic).
// Pass A -> save s*aggA in regs -> zero -> pass K -> combine epilogue.
// ---------------------------------------------------------------------------
__global__ __launch_bounds__(1024) void aggfix64(
    const int2* __restrict__ rawA, const int* __restrict__ boffA,
    const int2* __restrict__ rawK, const int* __restrict__ boffK,
    const unsigned short* __restrict__ feat, const float* __restrict__ s,
    const float* __restrict__ Dk, unsigned short* __restrict__ outp, int N) {
  __shared__ int acc[128 * 64];        // 32 KB
  const int tile = blockIdx.x;
  const int node0 = tile * 128;
  const int t = threadIdx.x;
  const int wid = t >> 6;
  const int h = t & 63;

#pragma unroll
  for (int u = 0; u < 8; ++u) acc[t + u * 1024] = 0;
  __syncthreads();

  // ---- pass A ----
  {
    int lo = boffA[tile], hi = boffA[tile + 1];
    int per = (hi - lo + 15) >> 4;
    int wb = lo + wid * per;
    int we = min(wb + per, hi);
    int j = wb;
    for (; j + 4 <= we; j += 4) {
      int2 r0 = rawA[j + 0];
      int2 r1 = rawA[j + 1];
      int2 r2 = rawA[j + 2];
      int2 r3 = rawA[j + 3];
      float f0 = bf2f(feat[(size_t)(r0.x & 0xFFFF) * 64 + h]);
      float f1 = bf2f(feat[(size_t)(r1.x & 0xFFFF) * 64 + h]);
      float f2 = bf2f(feat[(size_t)(r2.x & 0xFFFF) * 64 + h]);
      float f3 = bf2f(feat[(size_t)(r3.x & 0xFFFF) * 64 + h]);
      atomicAdd(&acc[((r0.x >> 16) & 127) * 64 + h],
                __float2int_rn(__int_as_float(r0.y) * f0 * SCALE0));
      atomicAdd(&acc[((r1.x >> 16) & 127) * 64 + h],
                __float2int_rn(__int_as_float(r1.y) * f1 * SCALE0));
      atomicAdd(&acc[((r2.x >> 16) & 127) * 64 + h],
                __float2int_rn(__int_as_float(r2.y) * f2 * SCALE0));
      atomicAdd(&acc[((r3.x >> 16) & 127) * 64 + h],
                __float2int_rn(__int_as_float(r3.y) * f3 * SCALE0));
    }
    for (; j < we; ++j) {
      int2 r = rawA[j];
      float f = bf2f(feat[(size_t)(r.x & 0xFFFF) * 64 + h]);
      atomicAdd(&acc[((r.x >> 16) & 127) * 64 + h],
                __float2int_rn(__int_as_float(r.y) * f * SCALE0));
    }
  }
  __syncthreads();

  float keep[8];
#pragma unroll
  for (int u = 0; u < 8; ++u) {
    int idx = t + u * 1024;
    int n = node0 + (idx >> 6);
    keep[u] = (n < N) ? s[n] * (float)acc[idx] * INV0 : 0.f;
  }
  __syncthreads();
#pragma unroll
  for (int u = 0; u < 8; ++u) acc[t + u * 1024] = 0;
  __syncthreads();

  // ---- pass K ----
  {
    int lo = boffK[tile], hi = boffK[tile + 1];
    int per = (hi - lo + 15) >> 4;
    int wb = lo + wid * per;
    int we = min(wb + per, hi);
    int j = wb;
    for (; j + 4 <= we; j += 4) {
      int2 r0 = rawK[j + 0];
      int2 r1 = rawK[j + 1];
      int2 r2 = rawK[j + 2];
      int2 r3 = rawK[j + 3];
      float f0 = bf2f(feat[(size_t)(r0.x & 0xFFFF) * 64 + h]);
      float f1 = bf2f(feat[(size_t)(r1.x & 0xFFFF) * 64 + h]);
      float f2 = bf2f(feat[(size_t)(r2.x & 0xFFFF) * 64 + h]);
      float f3 = bf2f(feat[(size_t)(r3.x & 0xFFFF) * 64 + h]);
      atomicAdd(&acc[((r0.x >> 16) & 127) * 64 + h],
                __float2int_rn(__int_as_float(r0.y) * f0 * SCALE0));
      atomicAdd(&acc[((r1.x >> 16) & 127) * 64 + h],
                __float2int_rn(__int_as_float(r1.y) * f1 * SCALE0));
      atomicAdd(&acc[((r2.x >> 16) & 127) * 64 + h],
                __float2int_rn(__int_as_float(r2.y) * f2 * SCALE0));
      atomicAdd(&acc[((r3.x >> 16) & 127) * 64 + h],
                __float2int_rn(__int_as_float(r3.y) * f3 * SCALE0));
    }
    for (; j < we; ++j) {
      int2 r = rawK[j];
      float f = bf2f(feat[(size_t)(r.x & 0xFFFF) * 64 + h]);
      atomicAdd(&acc[((r.x >> 16) & 127) * 64 + h],
                __float2int_rn(__int_as_float(r.y) * f * SCALE0));
    }
  }
  __syncthreads();

#pragma unroll
  for (int u = 0; u < 8; ++u) {
    int idx = t + u * 1024;
    int n = node0 + (idx >> 6);
    int h2 = idx & 63;
    if (n < N) {
      float res = keep[u] + (1.f - s[n]) * (float)acc[idx] * INV0 +
                  GAMMA * Dk[n] * bf2f(feat[(size_t)n * 64 + h2]);
      outp[(size_t)n * 64 + h2] = f2bf(res);
    }
  }
}

// ---------------------------------------------------------------------------
// aggfix16: layer-1 aggregation + combine (H=16). accA+accK both resident.
// 16 lanes per edge; 4 edges per wave concurrently.
// ---------------------------------------------------------------------------
__global__ __launch_bounds__(1024) void aggfix16(
    const int2* __restrict__ rawA, const int* __restrict__ boffA,
    const int2* __restrict__ rawK, const int* __restrict__ boffK,
    const unsigned short* __restrict__ feat, const float* __restrict__ s,
    const float* __restrict__ Dk, float* __restrict__ outp, int N) {
  __shared__ int accA[128 * 16];       // 8 KB
  __shared__ int accK[128 * 16];       // 8 KB
  const int tile = blockIdx.x;
  const int node0 = tile * 128;
  const int t = threadIdx.x;
  const int wid = t >> 6;
  const int lane = t & 63;
  const int eg = lane >> 4;            // 0..3: edge slot within wave
  const int h = lane & 15;

#pragma unroll
  for (int u = 0; u < 2; ++u) {
    accA[t + u * 1024] = 0;
    accK[t + u * 1024] = 0;
  }
  __syncthreads();

  // ---- pass A ----
  {
    int lo = boffA[tile], hi = boffA[tile + 1];
    int per = (hi - lo + 15) >> 4;
    int wb = lo + wid * per;
    int we = min(wb + per, hi);
    for (int j = wb + eg; j < we; j += 4) {
      int2 r = rawA[j];
      float f = bf2f(feat[(size_t)(r.x & 0xFFFF) * 16 + h]);
      atomicAdd(&accA[((r.x >> 16) & 127) * 16 + h],
                __float2int_rn(__int_as_float(r.y) * f * SCALE1));
    }
  }
  // ---- pass K (different array; no barrier needed between) ----
  {
    int lo = boffK[tile], hi = boffK[tile + 1];
    int per = (hi - lo + 15) >> 4;
    int wb = lo + wid * per;
    int we = min(wb + per, hi);
    for (int j = wb + eg; j < we; j += 4) {
      int2 r = rawK[j];
      float f = bf2f(feat[(size_t)(r.x & 0xFFFF) * 16 + h]);
      atomicAdd(&accK[((r.x >> 16) & 127) * 16 + h],
                __float2int_rn(__int_as_float(r.y) * f * SCALE1));
    }
  }
  __syncthreads();

#pragma unroll
  for (int u = 0; u < 2; ++u) {
    int idx = t + u * 1024;
    int n = node0 + (idx >> 4);
    int h2 = idx & 15;
    if (n < N) {
      float sv = s[n];
      float res = sv * (float)accA[idx] * INV1 +
                  (1.f - sv) * (float)accK[idx] * INV1 +
                  GAMMA * Dk[n] * bf2f(feat[(size_t)n * 16 + h2]);
      outp[(size_t)n * 16 + h2] = res;
    }
  }
}

// ---------------------------------------------------------------------------
extern "C" void kernel_launch(void* const* d_in, const int* in_sizes, int n_in,
                              void* d_out, int out_size, void* d_ws, size_t ws_size,
                              hipStream_t stream) {
  const float* x = (const float*)d_in[0];
  const int* edge_index = (const int*)d_in[1];
  const float* edge_weight = (const float*)d_in[2];
  const int* knn_edge_index = (const int*)d_in[3];
  const float* knn_edge_weight = (const float*)d_in[4];
  const float* W0 = (const float*)d_in[5];
  const float* W1 = (const float*)d_in[6];
  const float* score0 = (const float*)d_in[7];
  const float* sbias0 = (const float*)d_in[8];
  const float* score1 = (const float*)d_in[9];
  const float* sbias1 = (const float*)d_in[10];
  const float* Dk0 = (const float*)d_in[11];
  const float* Dbias0 = (const float*)d_in[12];
  const float* Dk1 = (const float*)d_in[13];
  const float* Dbias1 = (const float*)d_in[14];

  const int F = in_sizes[7];          // 500
  const int N = in_sizes[0] / F;      // 50000 (< 65536: src packed in 16 bits)
  const int E = in_sizes[2];          // 1.6M
  const int Ek = in_sizes[4];         // 1.0M
  (void)n_in; (void)ws_size; (void)out_size;

  const int nb = (N + 127) / 128;     // 391 dst tiles (<= 512)
  const int nchA = (E + BIN_CHUNK - 1) / BIN_CHUNK;
  const int nchK = (Ek + BIN_CHUNK - 1) / BIN_CHUNK;

  // ---- workspace bump allocator (256B-aligned slices) ----
  // recRaw persists through BOTH agg kernels now -> no union with xW.
  char* cur = (char*)d_ws;
  auto alloc = [&](size_t bytes) {
    char* p = cur;
    cur += (bytes + 255) & ~(size_t)255;
    return (void*)p;
  };
  float* sbuf = (float*)alloc((size_t)N * 4);
  float* dkbuf = (float*)alloc((size_t)N * 4);
  int* bcnt2 = (int*)alloc((size_t)2 * nb * 4);   // ONE slice (R2 lesson)
  int* bcntA = bcnt2;
  int* bcntK = bcnt2 + nb;
  int* boffA = (int*)alloc((size_t)(nb + 1) * 4);
  int* boffK = (int*)alloc((size_t)(nb + 1) * 4);
  int* gcurA = (int*)alloc((size_t)nb * 4);
  int* gcurK = (int*)alloc((size_t)nb * 4);
  int* pcnt = (int*)alloc((size_t)(nchA + nchK) * 512 * 4);
  int2* recRawA = (int2*)alloc((size_t)E * 8);
  int2* recRawK = (int2*)alloc((size_t)Ek * 8);
  unsigned short* Bt0 = (unsigned short*)alloc((size_t)80 * 512 * 2);
  unsigned short* Bt1 = (unsigned short*)alloc((size_t)32 * 64 * 2);
  unsigned short* xWb = (unsigned short*)alloc((size_t)N * 64 * 2);
  unsigned short* x1b = (unsigned short*)alloc((size_t)N * 64 * 2);
  unsigned short* xW1b = (unsigned short*)alloc((size_t)N * 16 * 2);

  const int gemmBlocksL0 = (N + 15) / 16;
  const int gemmBlocksL1 = (N + 31) / 32;

  // 1) setup: zero counters + both Bt builds
  setup_fused<<<172, 256, 0, stream>>>(bcnt2, 2 * nb, W0, score0, Dk0, Bt0, F,
                                       W1, score1, Dk1, Bt1);
  // 2) bucket counts (A+K), saving per-chunk histograms
  bucket_count2<<<nchA + nchK, 512, 0, stream>>>(edge_index, E, bcntA,
                                                 knn_edge_index, Ek, bcntK,
                                                 nchA, pcnt);
  // 3) scans
  bucket_scan2<<<2, 512, 0, stream>>>(bcntA, boffA, gcurA, bcntK, boffK,
                                      gcurK, nb);
  // 4) bin fill (reserve from pcnt, scatter 8B raw records)
  bin_fill2<<<nchA + nchK, 512, 0, stream>>>(edge_index, edge_weight, E,
                                             gcurA, recRawA, knn_edge_index,
                                             knn_edge_weight, Ek, gcurK,
                                             recRawK, nchA, pcnt);
  // 5) layer-0 GEMM
  mfma_linear_l0<5, 4, 80><<<gemmBlocksL0, 256, 0, stream>>>(
      x, Bt0, sbias0, Dbias0, xWb, sbuf, dkbuf, N, F);
  // 6) layer-0 aggregate+combine (fixed-point LDS)
  aggfix64<<<nb, 1024, 0, stream>>>(recRawA, boffA, recRawK, boffK, xWb,
                                    sbuf, dkbuf, x1b, N);
  // 7) layer-1 GEMM
  mfma_linear_bf<64, 2, 1, 32><<<gemmBlocksL1, 256, 0, stream>>>(
      x1b, Bt1, sbias1, Dbias1, xW1b, sbuf, dkbuf, N, 64);
  // 8) layer-1 aggregate+combine -> output
  aggfix16<<<nb, 1024, 0, stream>>>(recRawA, boffA, recRawK, boffK, xW1b,
                                    sbuf, dkbuf, (float*)d_out, N);
}

// Round 18
// 168.394 us; speedup vs baseline: 1.4024x; 1.4024x over previous
//
#include <hip/hip_runtime.h>
#include <math.h>

#define GAMMA 0.1f

typedef float f32x4 __attribute__((ext_vector_type(4)));
typedef short short4v __attribute__((ext_vector_type(4)));
typedef short short8 __attribute__((ext_vector_type(8)));

static __device__ __forceinline__ unsigned short f2bf(float f) {
  union { float f; unsigned u; } v; v.f = f;
  unsigned r = v.u + 0x7FFF + ((v.u >> 16) & 1);   // RNE
  return (unsigned short)(r >> 16);
}
static __device__ __forceinline__ float bf2f(unsigned short b) {
  union { unsigned u; float f; } v; v.u = ((unsigned)b) << 16;
  return v.f;
}

// ---------------------------------------------------------------------------
// Fused setup: zero counters + build both K-chunk-major Bt matrices.
// blocks [0,2): zero bcnt2; [2,162): Bt0 (80x512); [162,170): Bt1 (32x64).
// ---------------------------------------------------------------------------
__global__ __launch_bounds__(256) void setup_fused(
    int* __restrict__ bcnt2, int ncnt,
    const float* __restrict__ W0, const float* __restrict__ sc0,
    const float* __restrict__ dk0, unsigned short* __restrict__ Bt0, int F,
    const float* __restrict__ W1, const float* __restrict__ sc1,
    const float* __restrict__ dk1, unsigned short* __restrict__ Bt1) {
  int b = blockIdx.x;
  int t = threadIdx.x;
  if (b < 2) {
    int i = b * 256 + t;
    if (i < ncnt) bcnt2[i] = 0;
  } else if (b < 162) {
    int i = (b - 2) * 256 + t;           // [0, 40960)
    int c = i >> 9;                      // /512
    int k = i & 511;
    float v = 0.f;
    if (k < F) {
      if (c < 64) v = W0[(size_t)k * 64 + c];
      else if (c == 64) v = sc0[k];
      else if (c == 65) v = dk0[k];
    }
    Bt0[(size_t)((k >> 3) * 80 + c) * 8 + (k & 7)] = f2bf(v);
  } else {
    int i = (b - 162) * 256 + t;         // [0, 2048)
    int c = i >> 6;                      // /64
    int k = i & 63;
    float v;
    if (c < 16) v = W1[(size_t)k * 16 + c];
    else if (c == 16) v = sc1[k];
    else if (c == 17) v = dk1[k];
    else v = 0.f;
    Bt1[(size_t)((k >> 3) * 32 + c) * 8 + (k & 7)] = f2bf(v);
  }
}

// ---------------------------------------------------------------------------
// Layer-0 fused MFMA linear, LDS-staged A, high-occupancy (R13/R14 struct).
// RPB=16 rows, 4 waves = 4 K-slices (KSPLIT=4); 31KB LDS -> 5 blocks/CU.
// ---------------------------------------------------------------------------
template <int CFRAGS, int OUTFRAGS, int COLS>
__global__ __launch_bounds__(256) void mfma_linear_l0(
    const float* __restrict__ A, const unsigned short* __restrict__ Bt3,
    const float* __restrict__ sb, const float* __restrict__ db,
    unsigned short* __restrict__ outW, float* __restrict__ s,
    float* __restrict__ Dk, int N, int Kact) {
  constexpr int KPAD = 512;
  constexpr int KSPLIT = 4, RPB = 16;
  constexpr int KS_PER = (KPAD / 32) / KSPLIT;     // 4
  constexpr int H = OUTFRAGS * 16;
  __shared__ unsigned short Ald[RPB * KPAD];                  // 16 KB
  __shared__ float red[(KSPLIT - 1) * 64 * CFRAGS * 4];       // 15 KB

  const int t = threadIdx.x;
  const int rowBase = blockIdx.x * RPB;

#pragma unroll
  for (int it = 0; it < (RPB * KPAD) / (256 * 4); ++it) {
    int li = it * 1024 + t * 4;
    int row = li >> 9;
    int col = li & 511;
    int grow = rowBase + row;
    f32x4 v = (f32x4)0.f;
    if (grow < N && col < Kact)
      v = *(const f32x4*)(A + (size_t)grow * Kact + col);
    short4v b;
#pragma unroll
    for (int j = 0; j < 4; ++j) b[j] = (short)f2bf(v[j]);
    int byte = row * (KPAD * 2) + ((col * 2) ^ ((row & 7) << 4));
    *(short4v*)((char*)Ald + byte) = b;
  }
  __syncthreads();

  const int kslice = t >> 6;          // 0..3
  const int l = t & 63;
  const int kgrp = l >> 4;
  const int lc = l & 15;
  const int lrow = lc;
  const int rowD = rowBase + kgrp * 4;

  f32x4 acc[CFRAGS];
#pragma unroll
  for (int i = 0; i < CFRAGS; ++i) acc[i] = (f32x4)0.f;

  const int rbyte = lrow * (KPAD * 2);
  const int rswz = (lrow & 7) << 4;
#pragma unroll
  for (int kk = 0; kk < KS_PER; ++kk) {
    const int ks = kslice * KS_PER + kk;
    short8 av = *(const short8*)((char*)Ald +
                                 (rbyte + ((ks * 64 + kgrp * 16) ^ rswz)));
    const unsigned short* bbase =
        Bt3 + (size_t)((ks * 4 + kgrp) * COLS + lc) * 8;
#pragma unroll
    for (int fc = 0; fc < CFRAGS; ++fc) {
      short8 bv = *(const short8*)(bbase + fc * 128);
      acc[fc] = __builtin_amdgcn_mfma_f32_16x16x32_bf16(av, bv, acc[fc], 0, 0, 0);
    }
  }

  if (kslice > 0) {
    float* dst = red + ((kslice - 1) * 64 + l) * (CFRAGS * 4);
#pragma unroll
    for (int fc = 0; fc < CFRAGS; ++fc)
#pragma unroll
      for (int r = 0; r < 4; ++r) dst[fc * 4 + r] = acc[fc][r];
  }
  __syncthreads();
  if (kslice == 0) {
#pragma unroll
    for (int s2 = 1; s2 < KSPLIT; ++s2) {
      const float* src2 = red + ((s2 - 1) * 64 + l) * (CFRAGS * 4);
#pragma unroll
      for (int fc = 0; fc < CFRAGS; ++fc)
#pragma unroll
        for (int r = 0; r < 4; ++r) acc[fc][r] += src2[fc * 4 + r];
    }
#pragma unroll
    for (int fc = 0; fc < OUTFRAGS; ++fc) {
#pragma unroll
      for (int r = 0; r < 4; ++r) {
        int gr = rowD + r;
        if (gr < N) outW[(size_t)gr * H + fc * 16 + lc] = f2bf(acc[fc][r]);
      }
    }
    if (lc < 2) {
      f32x4 g = acc[CFRAGS - 1];
#pragma unroll
      for (int r = 0; r < 4; ++r) {
        int gr = rowD + r;
        if (gr < N) {
          if (lc == 0) s[gr] = 1.f / (1.f + expf(-(g[r] + sb[0])));
          else Dk[gr] = g[r] + db[0];
        }
      }
    }
  }
}

// ---------------------------------------------------------------------------
// Layer-1 fused MFMA linear (bf16 A, K=64). RPB=32, KSPLIT=2.
// ---------------------------------------------------------------------------
template <int KPAD, int CFRAGS, int OUTFRAGS, int COLS>
__global__ __launch_bounds__(256) void mfma_linear_bf(
    const unsigned short* __restrict__ Aptr, const unsigned short* __restrict__ Bt3,
    const float* __restrict__ sb, const float* __restrict__ db,
    unsigned short* __restrict__ outW, float* __restrict__ s,
    float* __restrict__ Dk, int N, int Kact) {
  constexpr int H = OUTFRAGS * 16;
  constexpr int KSPLIT = 2, RG = 2, RPB = 32;
  constexpr int KS_PER = (KPAD / 32) / KSPLIT;
  __shared__ float red[(KSPLIT - 1) * RG * 64 * CFRAGS * 4];

  const int w = threadIdx.x >> 6;
  const int rowgrp = w % RG;
  const int kslice = w / RG;
  const int l = threadIdx.x & 63;
  const int kgrp = l >> 4;
  const int lc = l & 15;
  const int rowA = blockIdx.x * RPB + rowgrp * 16 + lc;
  const int rowD = blockIdx.x * RPB + rowgrp * 16 + kgrp * 4;
  const int rowSafe = (rowA < N) ? rowA : 0;

  f32x4 acc[CFRAGS];
#pragma unroll
  for (int i = 0; i < CFRAGS; ++i) acc[i] = (f32x4)0.f;

#pragma unroll
  for (int kk = 0; kk < KS_PER; ++kk) {
    const int ks = kslice * KS_PER + kk;
    const int kb = ks * 32 + kgrp * 8;
    short8 av = *(const short8*)(Aptr + (size_t)rowSafe * Kact + kb);
    const unsigned short* bbase =
        Bt3 + (size_t)((ks * 4 + kgrp) * COLS + lc) * 8;
#pragma unroll
    for (int fc = 0; fc < CFRAGS; ++fc) {
      short8 bv = *(const short8*)(bbase + fc * 128);
      acc[fc] = __builtin_amdgcn_mfma_f32_16x16x32_bf16(av, bv, acc[fc], 0, 0, 0);
    }
  }

  if (kslice > 0) {
    float* dst = red + ((rowgrp)*64 + l) * (CFRAGS * 4);
#pragma unroll
    for (int fc = 0; fc < CFRAGS; ++fc)
#pragma unroll
      for (int r = 0; r < 4; ++r) dst[fc * 4 + r] = acc[fc][r];
  }
  __syncthreads();
  if (kslice == 0) {
    const float* src2 = red + ((rowgrp)*64 + l) * (CFRAGS * 4);
#pragma unroll
    for (int fc = 0; fc < CFRAGS; ++fc)
#pragma unroll
      for (int r = 0; r < 4; ++r) acc[fc][r] += src2[fc * 4 + r];

#pragma unroll
    for (int fc = 0; fc < OUTFRAGS; ++fc) {
#pragma unroll
      for (int r = 0; r < 4; ++r) {
        int gr = rowD + r;
        if (gr < N) outW[(size_t)gr * H + fc * 16 + lc] = f2bf(acc[fc][r]);
      }
    }
    if (lc < 2) {
      f32x4 g = acc[CFRAGS - 1];
#pragma unroll
      for (int r = 0; r < 4; ++r) {
        int gr = rowD + r;
        if (gr < N) {
          if (lc == 0) s[gr] = 1.f / (1.f + expf(-(g[r] + sb[0])));
          else Dk[gr] = g[r] + db[0];
        }
      }
    }
  }
}

// ---------------------------------------------------------------------------
// Tile binning, 256-node tiles (bucket = dst >> 8, nb <= 256), A+K fused.
// INT atomics only (R5 lesson). bucket_count SAVES per-chunk counts
// (pcnt[chunk][256]) so bin_fill skips its own histogram pass (R16).
// ---------------------------------------------------------------------------
#define BIN_CHUNK 8192

__global__ __launch_bounds__(512) void bucket_count2(
    const int* __restrict__ eiA, int EA, int* __restrict__ bcntA,
    const int* __restrict__ eiK, int EK, int* __restrict__ bcntK, int nchA,
    int* __restrict__ pcnt) {
  const int* ei;
  int E, chunk;
  int* bcnt;
  if (blockIdx.x < nchA) { ei = eiA; E = EA; bcnt = bcntA; chunk = blockIdx.x; }
  else { ei = eiK; E = EK; bcnt = bcntK; chunk = blockIdx.x - nchA; }
  __shared__ int lc[256];
  if (threadIdx.x < 256) lc[threadIdx.x] = 0;
  __syncthreads();
  const int base = chunk * BIN_CHUNK;
  for (int k = threadIdx.x; k < BIN_CHUNK; k += 512) {
    int e = base + k;
    if (e < E) atomicAdd(&lc[ei[E + e] >> 8], 1);
  }
  __syncthreads();
  if (threadIdx.x < 256) {
    int c = lc[threadIdx.x];
    pcnt[blockIdx.x * 256 + threadIdx.x] = c;   // saved for bin_fill
    if (c) atomicAdd(&bcnt[threadIdx.x], c);
  }
}

__global__ __launch_bounds__(512) void bucket_scan2(
    int* __restrict__ bcntA, int* __restrict__ boffA, int* __restrict__ gcurA,
    int* __restrict__ bcntK, int* __restrict__ boffK, int* __restrict__ gcurK,
    int nb) {
  int* bcnt = blockIdx.x ? bcntK : bcntA;
  int* boff = blockIdx.x ? boffK : boffA;
  int* gcur = blockIdx.x ? gcurK : gcurA;
  __shared__ int sh[512];
  int t = threadIdx.x;
  int v = (t < nb) ? bcnt[t] : 0;
  sh[t] = v;
  __syncthreads();
  int acc = v;
  for (int off = 1; off < 512; off <<= 1) {
    int xx = (t >= off) ? sh[t - off] : 0;
    __syncthreads();
    acc += xx;
    sh[t] = acc;
    __syncthreads();
  }
  if (t < nb) {
    boff[t] = acc - v;
    gcur[t] = acc - v;
  }
  if (t == nb - 1) boff[nb] = acc;
}

// Raw record: {x = (dst&255)<<16 | src, y = fp32 weight bits}
// Reserve runs from saved pcnt (no histogram pass), then scatter.
__global__ __launch_bounds__(512) void bin_fill2(
    const int* __restrict__ eiA, const float* __restrict__ ewA, int EA,
    int* __restrict__ gcurA, int2* __restrict__ recA,
    const int* __restrict__ eiK, const float* __restrict__ ewK, int EK,
    int* __restrict__ gcurK, int2* __restrict__ recK, int nchA,
    const int* __restrict__ pcnt) {
  const int* ei;
  const float* ew;
  int E, chunk;
  int* gcur;
  int2* rec;
  if (blockIdx.x < nchA) {
    ei = eiA; ew = ewA; E = EA; gcur = gcurA; rec = recA; chunk = blockIdx.x;
  } else {
    ei = eiK; ew = ewK; E = EK; gcur = gcurK; rec = recK;
    chunk = blockIdx.x - nchA;
  }
  __shared__ int scur[256];
  if (threadIdx.x < 256) {
    int c = pcnt[blockIdx.x * 256 + threadIdx.x];
    scur[threadIdx.x] = c ? atomicAdd(&gcur[threadIdx.x], c) : 0;
  }
  __syncthreads();
  const int base = chunk * BIN_CHUNK;
  for (int k = threadIdx.x; k < BIN_CHUNK; k += 512) {
    int e = base + k;
    if (e < E) {
      int src = ei[e];
      int dst = ei[E + e];
      int pos = atomicAdd(&scur[dst >> 8], 1);
      rec[pos] = make_int2(((dst & 255) << 16) | src, __float_as_int(ew[e]));
    }
  }
}

// ---------------------------------------------------------------------------
// tile_sort2: one block per 256-node tile (A tiles then K tiles).
// Writes PACKED 4B records: (wbf16 << 16) | src — dst implied by rp.
// ---------------------------------------------------------------------------
__global__ __launch_bounds__(512) void tile_sort2(
    const int2* __restrict__ recRawA, const int* __restrict__ boffA,
    unsigned* __restrict__ recSA, int* __restrict__ rpA,
    const int2* __restrict__ recRawK, const int* __restrict__ boffK,
    unsigned* __restrict__ recSK, int* __restrict__ rpK, int N, int nb) {
  const int2* recRaw;
  const int* boff;
  unsigned* recS;
  int* rp;
  int tile;
  if (blockIdx.x < nb) {
    recRaw = recRawA; boff = boffA; recS = recSA; rp = rpA; tile = blockIdx.x;
  } else {
    recRaw = recRawK; boff = boffK; recS = recSK; rp = rpK;
    tile = blockIdx.x - nb;
  }
  __shared__ int cnt[256];
  __shared__ int sc[256];
  __shared__ int cur[256];
  const int lo = boff[tile], hi = boff[tile + 1];
  const int t = threadIdx.x;
  if (t < 256) cnt[t] = 0;
  __syncthreads();
  for (int j = lo + t; j < hi; j += 512)
    atomicAdd(&cnt[recRaw[j].x >> 16], 1);
  __syncthreads();
  if (t < 256) sc[t] = cnt[t];
  __syncthreads();
  for (int off = 1; off < 256; off <<= 1) {
    int v = 0;
    if (t < 256 && t >= off) v = sc[t - off];
    __syncthreads();
    if (t < 256) sc[t] += v;
    __syncthreads();
  }
  if (t < 256) {
    int excl = sc[t] - cnt[t];
    cur[t] = excl;
    int n = tile * 256 + t;
    if (n < N) rp[n] = lo + excl;
  }
  if (tile == nb - 1 && t == 0) rp[N] = hi;
  __syncthreads();
  for (int j = lo + t; j < hi; j += 512) {
    int2 r = recRaw[j];
    int pos = lo + atomicAdd(&cur[r.x >> 16], 1);
    recS[pos] = ((unsigned)f2bf(__int_as_float(r.y)) << 16) |
                (unsigned)(r.x & 0xFFFF);
  }
}

// ---------------------------------------------------------------------------
// Layer-0 gather: one wave per node (64 feature lanes), 16 chains.
// 4B records: src = lo 16 bits, weight = bf16 in hi 16 bits.
// ---------------------------------------------------------------------------
static __device__ __forceinline__ float gather64(
    const int* __restrict__ rp, const unsigned* __restrict__ rec,
    const unsigned short* __restrict__ feat, int n, int h) {
  int b = rp[n], e = rp[n + 1];
  float a[16];
#pragma unroll
  for (int u = 0; u < 16; ++u) a[u] = 0.f;
  int j = b;
  for (; j + 16 <= e; j += 16) {
#pragma unroll
    for (int u = 0; u < 16; ++u) {
      unsigned r = rec[j + u];
      a[u] += bf2f((unsigned short)(r >> 16)) *
              bf2f(feat[(size_t)(r & 0xFFFF) * 64 + h]);
    }
  }
  for (; j + 4 <= e; j += 4) {
#pragma unroll
    for (int u = 0; u < 4; ++u) {
      unsigned r = rec[j + u];
      a[u] += bf2f((unsigned short)(r >> 16)) *
              bf2f(feat[(size_t)(r & 0xFFFF) * 64 + h]);
    }
  }
  for (; j < e; ++j) {
    unsigned r = rec[j];
    a[0] += bf2f((unsigned short)(r >> 16)) *
            bf2f(feat[(size_t)(r & 0xFFFF) * 64 + h]);
  }
  float t0 = ((a[0] + a[1]) + (a[2] + a[3])) + ((a[4] + a[5]) + (a[6] + a[7]));
  float t1 = ((a[8] + a[9]) + (a[10] + a[11])) +
             ((a[12] + a[13]) + (a[14] + a[15]));
  return t0 + t1;
}

__global__ __launch_bounds__(256) void agg_combine64(
    const int* __restrict__ rpA, const unsigned* __restrict__ recA,
    const int* __restrict__ rpK, const unsigned* __restrict__ recK,
    const unsigned short* __restrict__ feat, const float* __restrict__ s,
    const float* __restrict__ Dk, unsigned short* __restrict__ outp, int N) {
  int n = __builtin_amdgcn_readfirstlane((blockIdx.x * 256 + threadIdx.x) >> 6);
  if (n >= N) return;
  int h = threadIdx.x & 63;
  float aA = gather64(rpA, recA, feat, n, h);
  float aK = gather64(rpK, recK, feat, n, h);
  float sv = s[n];
  float res = sv * aA + (1.f - sv) * aK +
              GAMMA * Dk[n] * bf2f(feat[(size_t)n * 64 + h]);
  outp[(size_t)n * 64 + h] = f2bf(res);
}

// ---------------------------------------------------------------------------
// Layer-1 gather (H=16, 4 nodes per wave): 4B records, 8 chains.
// ---------------------------------------------------------------------------
static __device__ __forceinline__ float gather16(
    const int* __restrict__ rp, const unsigned* __restrict__ rec,
    const unsigned short* __restrict__ feat, int n, int h) {
  int b = rp[n], e = rp[n + 1];
  float a0 = 0.f, a1 = 0.f, a2 = 0.f, a3 = 0.f;
  float a4 = 0.f, a5 = 0.f, a6 = 0.f, a7 = 0.f;
  int j = b;
  for (; j + 8 <= e; j += 8) {
    unsigned q0 = rec[j + 0];
    unsigned q1 = rec[j + 1];
    unsigned q2 = rec[j + 2];
    unsigned q3 = rec[j + 3];
    unsigned q4 = rec[j + 4];
    unsigned q5 = rec[j + 5];
    unsigned q6 = rec[j + 6];
    unsigned q7 = rec[j + 7];
    a0 += bf2f((unsigned short)(q0 >> 16)) *
          bf2f(feat[(size_t)(q0 & 0xFFFF) * 16 + h]);
    a1 += bf2f((unsigned short)(q1 >> 16)) *
          bf2f(feat[(size_t)(q1 & 0xFFFF) * 16 + h]);
    a2 += bf2f((unsigned short)(q2 >> 16)) *
          bf2f(feat[(size_t)(q2 & 0xFFFF) * 16 + h]);
    a3 += bf2f((unsigned short)(q3 >> 16)) *
          bf2f(feat[(size_t)(q3 & 0xFFFF) * 16 + h]);
    a4 += bf2f((unsigned short)(q4 >> 16)) *
          bf2f(feat[(size_t)(q4 & 0xFFFF) * 16 + h]);
    a5 += bf2f((unsigned short)(q5 >> 16)) *
          bf2f(feat[(size_t)(q5 & 0xFFFF) * 16 + h]);
    a6 += bf2f((unsigned short)(q6 >> 16)) *
          bf2f(feat[(size_t)(q6 & 0xFFFF) * 16 + h]);
    a7 += bf2f((unsigned short)(q7 >> 16)) *
          bf2f(feat[(size_t)(q7 & 0xFFFF) * 16 + h]);
  }
  for (; j < e; ++j) {
    unsigned q = rec[j];
    a0 += bf2f((unsigned short)(q >> 16)) *
          bf2f(feat[(size_t)(q & 0xFFFF) * 16 + h]);
  }
  return ((a0 + a1) + (a2 + a3)) + ((a4 + a5) + (a6 + a7));
}

__global__ __launch_bounds__(256) void agg_combine16(
    const int* __restrict__ rpA, const unsigned* __restrict__ recA,
    const int* __restrict__ rpK, const unsigned* __restrict__ recK,
    const unsigned short* __restrict__ feat, const float* __restrict__ s,
    const float* __restrict__ Dk, float* __restrict__ outp, int N) {
  int tid = blockIdx.x * 256 + threadIdx.x;
  int n = tid >> 4;
  int h = tid & 15;
  if (n >= N) return;
  float aA = gather16(rpA, recA, feat, n, h);
  float aK = gather16(rpK, recK, feat, n, h);
  float sv = s[n];
  float res = sv * aA + (1.f - sv) * aK +
              GAMMA * Dk[n] * bf2f(feat[(size_t)n * 16 + h]);
  outp[(size_t)n * 16 + h] = res;
}

// ---------------------------------------------------------------------------
extern "C" void kernel_launch(void* const* d_in, const int* in_sizes, int n_in,
                              void* d_out, int out_size, void* d_ws, size_t ws_size,
                              hipStream_t stream) {
  const float* x = (const float*)d_in[0];
  const int* edge_index = (const int*)d_in[1];
  const float* edge_weight = (const float*)d_in[2];
  const int* knn_edge_index = (const int*)d_in[3];
  const float* knn_edge_weight = (const float*)d_in[4];
  const float* W0 = (const float*)d_in[5];
  const float* W1 = (const float*)d_in[6];
  const float* score0 = (const float*)d_in[7];
  const float* sbias0 = (const float*)d_in[8];
  const float* score1 = (const float*)d_in[9];
  const float* sbias1 = (const float*)d_in[10];
  const float* Dk0 = (const float*)d_in[11];
  const float* Dbias0 = (const float*)d_in[12];
  const float* Dk1 = (const float*)d_in[13];
  const float* Dbias1 = (const float*)d_in[14];

  const int F = in_sizes[7];          // 500
  const int N = in_sizes[0] / F;      // 50000 (< 65536: src packed in 16 bits)
  const int E = in_sizes[2];          // 1.6M
  const int Ek = in_sizes[4];         // 1.0M
  (void)n_in; (void)ws_size; (void)out_size;

  const int nb = (N + 255) / 256;     // 196 dst tiles (<= 256)
  const int nchA = (E + BIN_CHUNK - 1) / BIN_CHUNK;
  const int nchK = (Ek + BIN_CHUNK - 1) / BIN_CHUNK;

  // ---- workspace bump allocator (256B-aligned slices) — R14 layout ----
  char* cur = (char*)d_ws;
  auto alloc = [&](size_t bytes) {
    char* p = cur;
    cur += (bytes + 255) & ~(size_t)255;
    return (void*)p;
  };
  float* sbuf = (float*)alloc((size_t)N * 4);
  float* dkbuf = (float*)alloc((size_t)N * 4);
  int* bcnt2 = (int*)alloc((size_t)2 * nb * 4);   // ONE slice (R2 lesson)
  int* bcntA = bcnt2;
  int* bcntK = bcnt2 + nb;
  int* boffA = (int*)alloc((size_t)(nb + 1) * 4);
  int* boffK = (int*)alloc((size_t)(nb + 1) * 4);
  int* gcurA = (int*)alloc((size_t)nb * 4);
  int* gcurK = (int*)alloc((size_t)nb * 4);
  int* rpA = (int*)alloc((size_t)(N + 1) * 4);
  int* rpK = (int*)alloc((size_t)(N + 1) * 4);
  int* pcnt = (int*)alloc((size_t)(nchA + nchK) * 256 * 4);  // saved counts
  unsigned* recA = (unsigned*)alloc((size_t)E * 4);   // sorted, PACKED 4B
  unsigned* recK = (unsigned*)alloc((size_t)Ek * 4);
  unsigned short* Bt0 = (unsigned short*)alloc((size_t)80 * 512 * 2);
  unsigned short* Bt1 = (unsigned short*)alloc((size_t)32 * 64 * 2);
  // UNION region: recRaw (dead after tile_sort) overlaps the feature buffers
  // (written only after tile_sort completes; same stream => safe).
  char* uni = (char*)alloc((size_t)(E + Ek) * 8);
  int2* recRawA = (int2*)uni;
  int2* recRawK = recRawA + E;
  unsigned short* xWb = (unsigned short*)uni;              // N*64
  unsigned short* x1b = xWb + (size_t)N * 64;              // N*64
  unsigned short* xW1b = x1b + (size_t)N * 64;             // N*16

  const int gemmBlocksL0 = (N + 15) / 16;
  const int gemmBlocksL1 = (N + 31) / 32;
  const int agg64Blocks = (int)(((size_t)N * 64 + 255) / 256);
  const int agg16Blocks = (int)(((size_t)N * 16 + 255) / 256);

  // 1) setup: zero counters + both Bt builds (one launch)
  setup_fused<<<170, 256, 0, stream>>>(bcnt2, 2 * nb, W0, score0, Dk0, Bt0, F,
                                       W1, score1, Dk1, Bt1);
  // 2) bucket counts (A+K), saving per-chunk histograms
  bucket_count2<<<nchA + nchK, 512, 0, stream>>>(edge_index, E, bcntA,
                                                 knn_edge_index, Ek, bcntK,
                                                 nchA, pcnt);
  // 3) scans
  bucket_scan2<<<2, 512, 0, stream>>>(bcntA, boffA, gcurA, bcntK, boffK,
                                      gcurK, nb);
  // 4) bin fill (reserve from pcnt, scatter — no histogram pass)
  bin_fill2<<<nchA + nchK, 512, 0, stream>>>(edge_index, edge_weight, E,
                                             gcurA, recRawA, knn_edge_index,
                                             knn_edge_weight, Ek, gcurK,
                                             recRawK, nchA, pcnt);
  // 5) tile sort (exact CSR, packed 4B records)
  tile_sort2<<<2 * nb, 512, 0, stream>>>(recRawA, boffA, recA, rpA, recRawK,
                                         boffK, recK, rpK, N, nb);
  // 6) layer-0 GEMM
  mfma_linear_l0<5, 4, 80><<<gemmBlocksL0, 256, 0, stream>>>(
      x, Bt0, sbias0, Dbias0, xWb, sbuf, dkbuf, N, F);
  // 7) layer-0 aggregate+combine
  agg_combine64<<<agg64Blocks, 256, 0, stream>>>(rpA, recA, rpK, recK, xWb,
                                                 sbuf, dkbuf, x1b, N);
  // 8) layer-1 GEMM
  mfma_linear_bf<64, 2, 1, 32><<<gemmBlocksL1, 256, 0, stream>>>(
      x1b, Bt1, sbias1, Dbias1, xW1b, sbuf, dkbuf, N, 64);
  // 9) layer-1 aggregate+combine -> output
  agg_combine16<<<agg16Blocks, 256, 0, stream>>>(rpA, recA, rpK, recK, xW1b,
                                                 sbuf, dkbuf, (float*)d_out, N);
}